// Round 1
// baseline (1567.307 us; speedup 1.0000x reference)
//
#include <hip/hip_runtime.h>
#include <math.h>

#define SCALAR_SCALE 0.14433756729740643f  /* 1/sqrt(48) */
#define POINT_SCALE  0.13608276348795434f  /* 1/sqrt(54) */
#define PAIR_SCALE   0.5773502691896258f   /* 1/sqrt(3)  */

// ---------------------------------------------------------------------------
// Kernel A: pair_bias[h][i][j] = bpb[h] + sum_d pair[i][j][d] * Wpb[d][h]
// One wave handles 8 consecutive (i,j) pairs. lane = h*8+g; lane sums 48 d's.
// ---------------------------------------------------------------------------
__global__ __launch_bounds__(256) void k_pair_bias(
    const float* __restrict__ pair, const float* __restrict__ Wpb,
    const float* __restrict__ bpb, float* __restrict__ pb) {
  __shared__ float sW[384 * 8];
  for (int t = threadIdx.x; t < 384 * 8; t += 256) sW[t] = Wpb[t];
  __syncthreads();
  int wave = threadIdx.x >> 6;
  int lane = threadIdx.x & 63;
  int h = lane >> 3, g = lane & 7;
  float w[48];
#pragma unroll
  for (int k = 0; k < 48; ++k) w[k] = sW[(g * 48 + k) * 8 + h];
  int gw = blockIdx.x * 4 + wave;   // global wave id, 32768 total
  int p0 = gw * 8;                  // first pair index
  int i = p0 >> 9;
  int j0 = p0 & 511;
  const float* base = pair + ((size_t)(i * 512 + j0)) * 384 + g * 48;
  float acc[8];
#pragma unroll
  for (int jo = 0; jo < 8; ++jo) {
    const float4* p4 = (const float4*)(base + jo * 384);
    float a = 0.f;
#pragma unroll
    for (int k = 0; k < 12; ++k) {
      float4 v = p4[k];
      a = fmaf(v.x, w[k * 4 + 0], a);
      a = fmaf(v.y, w[k * 4 + 1], a);
      a = fmaf(v.z, w[k * 4 + 2], a);
      a = fmaf(v.w, w[k * 4 + 3], a);
    }
    acc[jo] = a;
  }
#pragma unroll
  for (int m = 1; m <= 4; m <<= 1) {
#pragma unroll
    for (int jo = 0; jo < 8; ++jo) acc[jo] += __shfl_xor(acc[jo], m, 64);
  }
  // static select acc[g] (avoid runtime-indexed array -> scratch)
  float outv = acc[0];
#pragma unroll
  for (int jo = 1; jo < 8; ++jo) if (g == jo) outv = acc[jo];
  pb[((h * 512 + i) << 9) + j0 + g] = outv + bpb[h];
}

// ---------------------------------------------------------------------------
// Kernel B1: raw[n][672] = x[n][:] @ [Wsq|Wsk|Wsv|Wpq|Wpk|Wpv]
// ---------------------------------------------------------------------------
__global__ __launch_bounds__(256) void k_proj(
    const float* __restrict__ x,
    const float* __restrict__ Wsq, const float* __restrict__ Wsk,
    const float* __restrict__ Wsv, const float* __restrict__ Wpq,
    const float* __restrict__ Wpk, const float* __restrict__ Wpv,
    float* __restrict__ raw) {
  __shared__ float Xs[16][389];  // pad 389: 16 rows hit distinct banks
  int nb = blockIdx.x, cb = blockIdx.y;
  int c0 = cb * 16;
  const float* W; int stride, coff;
  if (c0 < 128)      { W = Wsq; stride = 128; coff = c0; }
  else if (c0 < 256) { W = Wsk; stride = 128; coff = c0 - 128; }
  else if (c0 < 384) { W = Wsv; stride = 128; coff = c0 - 256; }
  else if (c0 < 480) { W = Wpq; stride = 96;  coff = c0 - 384; }
  else if (c0 < 576) { W = Wpk; stride = 96;  coff = c0 - 480; }
  else               { W = Wpv; stride = 96;  coff = c0 - 576; }
  for (int t = threadIdx.x; t < 16 * 384; t += 256) {
    int nl = t / 384, d = t - nl * 384;
    Xs[nl][d] = x[(nb * 16 + nl) * 384 + d];
  }
  __syncthreads();
  int nl = threadIdx.x >> 4, cl = threadIdx.x & 15;
  const float* Wc = W + coff + cl;
  float acc = 0.f;
#pragma unroll 8
  for (int d = 0; d < 384; ++d) acc = fmaf(Xs[nl][d], Wc[d * stride], acc);
  raw[(nb * 16 + nl) * 672 + c0 + cl] = acc;
}

// ---------------------------------------------------------------------------
// Kernel B2: per-n — R from quaternion, reshape qs/ks/vs, rotate qp/kp/vp,
// q2/k2 precompute. Layouts: s: [h][n][16], p: [h][n][12].
// ---------------------------------------------------------------------------
__global__ __launch_bounds__(64) void k_prep(
    const float* __restrict__ raw, const float* __restrict__ quat,
    const float* __restrict__ trans,
    float* __restrict__ qs, float* __restrict__ ks, float* __restrict__ vs,
    float* __restrict__ qp, float* __restrict__ kp, float* __restrict__ vp,
    float* __restrict__ q2, float* __restrict__ k2, float* __restrict__ Rm) {
  int n = blockIdx.x * 64 + threadIdx.x;
  float qw = quat[n * 4 + 0], qx = quat[n * 4 + 1];
  float qy = quat[n * 4 + 2], qz = quat[n * 4 + 3];
  float ss = 2.f / (qw * qw + qx * qx + qy * qy + qz * qz);
  float R00 = 1.f - ss * (qy * qy + qz * qz);
  float R01 = ss * (qx * qy - qz * qw);
  float R02 = ss * (qx * qz + qy * qw);
  float R10 = ss * (qx * qy + qz * qw);
  float R11 = 1.f - ss * (qx * qx + qz * qz);
  float R12 = ss * (qy * qz - qx * qw);
  float R20 = ss * (qx * qz - qy * qw);
  float R21 = ss * (qy * qz + qx * qw);
  float R22 = 1.f - ss * (qx * qx + qy * qy);
  float* Rr = Rm + n * 9;
  Rr[0] = R00; Rr[1] = R01; Rr[2] = R02;
  Rr[3] = R10; Rr[4] = R11; Rr[5] = R12;
  Rr[6] = R20; Rr[7] = R21; Rr[8] = R22;
  float t0 = trans[n * 3 + 0], t1 = trans[n * 3 + 1], t2 = trans[n * 3 + 2];
  const float* rr = raw + n * 672;
  for (int h = 0; h < 8; ++h) {
    int bs = (h * 512 + n) * 16;
#pragma unroll
    for (int d = 0; d < 16; ++d) {
      qs[bs + d] = rr[h * 16 + d];
      ks[bs + d] = rr[128 + h * 16 + d];
      vs[bs + d] = rr[256 + h * 16 + d];
    }
    float q2s = 0.f, k2s = 0.f;
    int bp = (h * 512 + n) * 12;
#pragma unroll
    for (int d = 0; d < 4; ++d) {
      float c0, c1, c2, o0, o1, o2;
      // qp: rotated point = p @ R + t (out[r] = sum_c p[c]*R[c][r] + t[r])
      c0 = rr[384 + h * 12 + d * 3 + 0];
      c1 = rr[384 + h * 12 + d * 3 + 1];
      c2 = rr[384 + h * 12 + d * 3 + 2];
      o0 = c0 * R00 + c1 * R10 + c2 * R20 + t0;
      o1 = c0 * R01 + c1 * R11 + c2 * R21 + t1;
      o2 = c0 * R02 + c1 * R12 + c2 * R22 + t2;
      qp[bp + d * 3 + 0] = o0; qp[bp + d * 3 + 1] = o1; qp[bp + d * 3 + 2] = o2;
      q2s += o0 * o0 + o1 * o1 + o2 * o2;
      c0 = rr[480 + h * 12 + d * 3 + 0];
      c1 = rr[480 + h * 12 + d * 3 + 1];
      c2 = rr[480 + h * 12 + d * 3 + 2];
      o0 = c0 * R00 + c1 * R10 + c2 * R20 + t0;
      o1 = c0 * R01 + c1 * R11 + c2 * R21 + t1;
      o2 = c0 * R02 + c1 * R12 + c2 * R22 + t2;
      kp[bp + d * 3 + 0] = o0; kp[bp + d * 3 + 1] = o1; kp[bp + d * 3 + 2] = o2;
      k2s += o0 * o0 + o1 * o1 + o2 * o2;
      c0 = rr[576 + h * 12 + d * 3 + 0];
      c1 = rr[576 + h * 12 + d * 3 + 1];
      c2 = rr[576 + h * 12 + d * 3 + 2];
      o0 = c0 * R00 + c1 * R10 + c2 * R20 + t0;
      o1 = c0 * R01 + c1 * R11 + c2 * R21 + t1;
      o2 = c0 * R02 + c1 * R12 + c2 * R22 + t2;
      vp[bp + d * 3 + 0] = o0; vp[bp + d * 3 + 1] = o1; vp[bp + d * 3 + 2] = o2;
    }
    q2[h * 512 + n] = q2s;
    k2[h * 512 + n] = k2s;
  }
}

// ---------------------------------------------------------------------------
// Kernel C: attention per (h,i). Logits -> softmax -> res_s/res_p.
// Writes normalized attn row (for res_pair pass) and cat[i] slices.
// ---------------------------------------------------------------------------
__global__ __launch_bounds__(256) void k_attn(
    const float* __restrict__ qs, const float* __restrict__ ks,
    const float* __restrict__ vs, const float* __restrict__ qp,
    const float* __restrict__ kp, const float* __restrict__ vp,
    const float* __restrict__ q2, const float* __restrict__ k2,
    const float* __restrict__ pb, const float* __restrict__ pw_raw,
    const float* __restrict__ Rm, const float* __restrict__ trans,
    float* __restrict__ attn, float* __restrict__ cat) {
  int i = blockIdx.x, h = blockIdx.y;
  int t = threadIdx.x;
  __shared__ float sq[16], sp[12];
  __shared__ float sattn[512];
  __shared__ float red[8][32];
  __shared__ float swr[4], sws[4];
  __shared__ float sres[28];
  if (t < 16) sq[t] = qs[((h << 9) + i) * 16 + t];
  else if (t < 28) sp[t - 16] = qp[((h << 9) + i) * 12 + (t - 16)];
  __syncthreads();
  float pwh = log1pf(expf(pw_raw[h]));  // softplus
  float q2i = q2[(h << 9) + i];
  float coef = 0.5f * POINT_SCALE * pwh;
  float lg[2];
#pragma unroll
  for (int p = 0; p < 2; ++p) {
    int j = t + (p << 8);
    const float4* k4 = (const float4*)(ks + ((h << 9) + j) * 16);
    float d16 = 0.f;
#pragma unroll
    for (int q4 = 0; q4 < 4; ++q4) {
      float4 kv = k4[q4];
      d16 = fmaf(kv.x, sq[q4 * 4 + 0], d16);
      d16 = fmaf(kv.y, sq[q4 * 4 + 1], d16);
      d16 = fmaf(kv.z, sq[q4 * 4 + 2], d16);
      d16 = fmaf(kv.w, sq[q4 * 4 + 3], d16);
    }
    const float4* p4 = (const float4*)(kp + ((h << 9) + j) * 12);
    float d12 = 0.f;
#pragma unroll
    for (int q4 = 0; q4 < 3; ++q4) {
      float4 kv = p4[q4];
      d12 = fmaf(kv.x, sp[q4 * 4 + 0], d12);
      d12 = fmaf(kv.y, sp[q4 * 4 + 1], d12);
      d12 = fmaf(kv.z, sp[q4 * 4 + 2], d12);
      d12 = fmaf(kv.w, sp[q4 * 4 + 3], d12);
    }
    float dist = q2i + k2[(h << 9) + j] - 2.f * d12;
    lg[p] = SCALAR_SCALE * d16 - coef * dist +
            PAIR_SCALE * pb[(((h << 9) + i) << 9) + j];
  }
  // block max
  float mx = fmaxf(lg[0], lg[1]);
#pragma unroll
  for (int m = 1; m < 64; m <<= 1) mx = fmaxf(mx, __shfl_xor(mx, m, 64));
  if ((t & 63) == 0) swr[t >> 6] = mx;
  __syncthreads();
  mx = fmaxf(fmaxf(swr[0], swr[1]), fmaxf(swr[2], swr[3]));
  float e0 = expf(lg[0] - mx), e1 = expf(lg[1] - mx);
  float sm = e0 + e1;
#pragma unroll
  for (int m = 1; m < 64; m <<= 1) sm += __shfl_xor(sm, m, 64);
  if ((t & 63) == 0) sws[t >> 6] = sm;
  __syncthreads();
  sm = sws[0] + sws[1] + sws[2] + sws[3];
  float inv = 1.f / sm;
  e0 *= inv; e1 *= inv;
  sattn[t] = e0; sattn[t + 256] = e1;
  {
    float* arow = attn + ((size_t)(((h << 9) + i)) << 9);
    arow[t] = e0; arow[t + 256] = e1;
  }
  __syncthreads();
  // res_s (16) + res_p (12): output o, 8 j-groups of 64
  int o = t & 31, g = t >> 5;
  float partial = 0.f;
  if (o < 28) {
    const float* src; int stride;
    if (o < 16) { src = vs + (h << 9) * 16 + o; stride = 16; }
    else        { src = vp + (h << 9) * 12 + (o - 16); stride = 12; }
    int j0 = g << 6;
    for (int j = j0; j < j0 + 64; ++j)
      partial = fmaf(sattn[j], src[j * stride], partial);
  }
  red[g][o] = partial;
  __syncthreads();
  if (t < 28) {
    float r2 = 0.f;
#pragma unroll
    for (int gg = 0; gg < 8; ++gg) r2 += red[gg][t];
    sres[t] = r2;
  }
  __syncthreads();
  float* crow = cat + i * 3328;
  if (t < 16) {
    crow[h * 16 + t] = sres[t];                 // merged res_s
  } else if (t < 20) {
    int d = t - 16;
    float t0 = trans[i * 3], t1 = trans[i * 3 + 1], t2 = trans[i * 3 + 2];
    float c0 = sres[16 + d * 3 + 0] - t0;
    float c1 = sres[16 + d * 3 + 1] - t1;
    float c2 = sres[16 + d * 3 + 2] - t2;
    const float* R = Rm + i * 9;
    // local[r] = sum_c c[c]*R[r][c]  (inverse frame)
    float l0 = c0 * R[0] + c1 * R[1] + c2 * R[2];
    float l1 = c0 * R[3] + c1 * R[4] + c2 * R[5];
    float l2 = c0 * R[6] + c1 * R[7] + c2 * R[8];
    crow[128 + h * 12 + d * 3 + 0] = l0;
    crow[128 + h * 12 + d * 3 + 1] = l1;
    crow[128 + h * 12 + d * 3 + 2] = l2;
    crow[224 + h * 4 + d] = sqrtf(l0 * l0 + l1 * l1 + l2 * l2 + 1e-8f);
  }
}

// ---------------------------------------------------------------------------
// Kernel D: res_pair[h][i][d] = sum_j attn[h][i][j] * pair[i][j][d]
// Block per i, thread per d (384 threads), attn rows in LDS.
// ---------------------------------------------------------------------------
__global__ __launch_bounds__(384) void k_respair(
    const float* __restrict__ attn, const float* __restrict__ pair,
    float* __restrict__ cat) {
  __shared__ float sa[8][512];
  int i = blockIdx.x;
  for (int t = threadIdx.x; t < 4096; t += 384) {
    int h = t >> 9, j = t & 511;
    sa[h][j] = attn[((size_t)(h * 512 + i) << 9) + j];
  }
  __syncthreads();
  int d = threadIdx.x;
  float acc[8] = {0.f, 0.f, 0.f, 0.f, 0.f, 0.f, 0.f, 0.f};
  const float* p = pair + (size_t)i * 512 * 384 + d;
  for (int j = 0; j < 512; j += 4) {
    float v0 = p[(size_t)(j + 0) * 384];
    float v1 = p[(size_t)(j + 1) * 384];
    float v2 = p[(size_t)(j + 2) * 384];
    float v3 = p[(size_t)(j + 3) * 384];
#pragma unroll
    for (int h = 0; h < 8; ++h) {
      float4 a4 = *(const float4*)&sa[h][j];
      acc[h] = fmaf(a4.x, v0, acc[h]);
      acc[h] = fmaf(a4.y, v1, acc[h]);
      acc[h] = fmaf(a4.z, v2, acc[h]);
      acc[h] = fmaf(a4.w, v3, acc[h]);
    }
  }
#pragma unroll
  for (int h = 0; h < 8; ++h) cat[i * 3328 + 256 + h * 384 + d] = acc[h];
}

// ---------------------------------------------------------------------------
// Generic f32 GEMM: out[M][Ncols] = A[M][K] @ W[K][Ncols] (+bias, +resid, relu)
// 64x64 tile, K-chunk 32, 256 threads, 4x4 per thread. M=512 fixed by grid.
// ---------------------------------------------------------------------------
__global__ __launch_bounds__(256) void k_gemm(
    const float* __restrict__ A, const float* __restrict__ W,
    const float* __restrict__ bias, const float* __restrict__ resid,
    float* __restrict__ out, int K, int Ncols, int relu) {
  __shared__ float As[64][33];
  __shared__ float Ws[32][65];
  int rb = blockIdx.x << 6, cb = blockIdx.y << 6;
  int tr = (threadIdx.x >> 4) << 2, tc = (threadIdx.x & 15) << 2;
  float acc[4][4] = {};
  for (int k0 = 0; k0 < K; k0 += 32) {
    for (int t = threadIdx.x; t < 2048; t += 256) {
      int r = t >> 5, k = t & 31;
      As[r][k] = A[(rb + r) * K + k0 + k];
      int kk = t >> 6, c = t & 63;
      Ws[kk][c] = W[(k0 + kk) * Ncols + cb + c];
    }
    __syncthreads();
#pragma unroll
    for (int k = 0; k < 32; ++k) {
      float av[4], wv[4];
#pragma unroll
      for (int r = 0; r < 4; ++r) av[r] = As[tr + r][k];
#pragma unroll
      for (int c = 0; c < 4; ++c) wv[c] = Ws[k][tc + c];
#pragma unroll
      for (int r = 0; r < 4; ++r)
#pragma unroll
        for (int c = 0; c < 4; ++c) acc[r][c] = fmaf(av[r], wv[c], acc[r][c]);
    }
    __syncthreads();
  }
#pragma unroll
  for (int r = 0; r < 4; ++r) {
    int row = rb + tr + r;
#pragma unroll
    for (int c = 0; c < 4; ++c) {
      int col = cb + tc + c;
      float v = acc[r][c] + bias[col];
      if (resid) v += resid[row * Ncols + col];
      if (relu) v = fmaxf(v, 0.f);
      out[row * Ncols + col] = v;
    }
  }
}

// ---------------------------------------------------------------------------
// LayerNorm over D=384, one wave per row.
// ---------------------------------------------------------------------------
__global__ __launch_bounds__(64) void k_ln(
    const float* __restrict__ in, const float* __restrict__ gw,
    const float* __restrict__ bw, float* __restrict__ out) {
  int n = blockIdx.x, lane = threadIdx.x;
  float v[6];
  float s1 = 0.f, s2 = 0.f;
#pragma unroll
  for (int k = 0; k < 3; ++k) {
    float2 xv = *(const float2*)(in + n * 384 + (k << 7) + (lane << 1));
    v[k * 2] = xv.x; v[k * 2 + 1] = xv.y;
    s1 += xv.x + xv.y;
    s2 = fmaf(xv.x, xv.x, fmaf(xv.y, xv.y, s2));
  }
#pragma unroll
  for (int m = 1; m < 64; m <<= 1) {
    s1 += __shfl_xor(s1, m, 64);
    s2 += __shfl_xor(s2, m, 64);
  }
  float mean = s1 * (1.f / 384.f);
  float var = s2 * (1.f / 384.f) - mean * mean;
  float inv = 1.f / sqrtf(var + 1e-5f);
#pragma unroll
  for (int k = 0; k < 3; ++k) {
    int d = (k << 7) + (lane << 1);
    out[n * 384 + d]     = (v[k * 2]     - mean) * inv * gw[d]     + bw[d];
    out[n * 384 + d + 1] = (v[k * 2 + 1] - mean) * inv * gw[d + 1] + bw[d + 1];
  }
}

// ---------------------------------------------------------------------------
// Final: updates = x2 @ Wproj + bproj; quaternion multiply; translation update
// ---------------------------------------------------------------------------
__global__ __launch_bounds__(64) void k_final(
    const float* __restrict__ x2, const float* __restrict__ Wproj,
    const float* __restrict__ bproj, const float* __restrict__ quat,
    const float* __restrict__ trans, const float* __restrict__ Rm,
    float* __restrict__ out) {
  int n = blockIdx.x * 64 + threadIdx.x;
  float u0 = bproj[0], u1 = bproj[1], u2 = bproj[2];
  float u3 = bproj[3], u4 = bproj[4], u5 = bproj[5];
  const float* xr = x2 + n * 384;
  for (int d = 0; d < 384; ++d) {
    float xv = xr[d];
    const float* wr = Wproj + d * 6;
    u0 = fmaf(xv, wr[0], u0); u1 = fmaf(xv, wr[1], u1); u2 = fmaf(xv, wr[2], u2);
    u3 = fmaf(xv, wr[3], u3); u4 = fmaf(xv, wr[4], u4); u5 = fmaf(xv, wr[5], u5);
  }
  float aw = quat[n * 4 + 0], ax = quat[n * 4 + 1];
  float ay = quat[n * 4 + 2], az = quat[n * 4 + 3];
  // b = (1, u0, u1, u2)
  float qw2 = aw - ax * u0 - ay * u1 - az * u2;
  float qx2 = aw * u0 + ax + ay * u2 - az * u1;
  float qy2 = aw * u1 - ax * u2 + ay + az * u0;
  float qz2 = aw * u2 + ax * u1 - ay * u0 + az;
  const float* R = Rm + n * 9;
  // t_new[r] = t[r] + sum_c u[3+c] * R[c][r]
  out[n * 3 + 0] = trans[n * 3 + 0] + u3 * R[0] + u4 * R[3] + u5 * R[6];
  out[n * 3 + 1] = trans[n * 3 + 1] + u3 * R[1] + u4 * R[4] + u5 * R[7];
  out[n * 3 + 2] = trans[n * 3 + 2] + u3 * R[2] + u4 * R[5] + u5 * R[8];
  out[1536 + n * 4 + 0] = qw2;
  out[1536 + n * 4 + 1] = qx2;
  out[1536 + n * 4 + 2] = qy2;
  out[1536 + n * 4 + 3] = qz2;
}

// ---------------------------------------------------------------------------
extern "C" void kernel_launch(void* const* d_in, const int* in_sizes, int n_in,
                              void* d_out, int out_size, void* d_ws,
                              size_t ws_size, hipStream_t stream) {
  const float* x_in   = (const float*)d_in[0];
  const float* pair   = (const float*)d_in[1];
  const float* trans  = (const float*)d_in[2];
  const float* quat   = (const float*)d_in[3];
  const float* Wsq    = (const float*)d_in[4];
  const float* Wsk    = (const float*)d_in[5];
  const float* Wsv    = (const float*)d_in[6];
  const float* Wpq    = (const float*)d_in[7];
  const float* Wpk    = (const float*)d_in[8];
  const float* Wpv    = (const float*)d_in[9];
  const float* pw     = (const float*)d_in[10];
  const float* Wpb    = (const float*)d_in[11];
  const float* bpb    = (const float*)d_in[12];
  const float* Wout   = (const float*)d_in[13];
  const float* bout   = (const float*)d_in[14];
  const float* attn_g = (const float*)d_in[15];
  const float* attn_b = (const float*)d_in[16];
  const float* W1     = (const float*)d_in[17];
  const float* b1     = (const float*)d_in[18];
  const float* W2     = (const float*)d_in[19];
  const float* b2     = (const float*)d_in[20];
  const float* W3     = (const float*)d_in[21];
  const float* b3     = (const float*)d_in[22];
  const float* ff_g   = (const float*)d_in[23];
  const float* ff_b   = (const float*)d_in[24];
  const float* Wproj  = (const float*)d_in[25];
  const float* bproj  = (const float*)d_in[26];

  float* ws   = (float*)d_ws;
  float* pb   = ws + 0;         // 2,097,152
  float* attn = ws + 2097152;   // 2,097,152
  float* raw  = ws + 4194304;   //   344,064
  float* qs   = ws + 4538368;   //    65,536
  float* ks_  = ws + 4603904;   //    65,536
  float* vs   = ws + 4669440;   //    65,536
  float* qp   = ws + 4734976;   //    49,152
  float* kp   = ws + 4784128;   //    49,152
  float* vp   = ws + 4833280;   //    49,152
  float* q2   = ws + 4882432;   //     4,096
  float* k2   = ws + 4886528;   //     4,096
  float* Rm   = ws + 4890624;   //     4,608
  float* cat  = ws + 4895232;   // 1,703,936
  float* ao   = ws + 6599168;   //   196,608
  float* xln  = ws + 6795776;   //   196,608
  float* ffa  = ws + 6992384;   //   196,608
  float* ffb  = ws + 7188992;   //   196,608
  float* x2   = ws + 7385600;   //   196,608  (total 7,582,208 f32 = 29 MB)

  k_pair_bias<<<8192, 256, 0, stream>>>(pair, Wpb, bpb, pb);
  k_proj<<<dim3(32, 42), 256, 0, stream>>>(x_in, Wsq, Wsk, Wsv, Wpq, Wpk, Wpv, raw);
  k_prep<<<8, 64, 0, stream>>>(raw, quat, trans, qs, ks_, vs, qp, kp, vp, q2, k2, Rm);
  k_attn<<<dim3(512, 8), 256, 0, stream>>>(qs, ks_, vs, qp, kp, vp, q2, k2, pb,
                                           pw, Rm, trans, attn, cat);
  k_respair<<<512, 384, 0, stream>>>(attn, pair, cat);
  // attn_out = cat @ Wout + bout + target_seq ; then LN -> xln
  k_gemm<<<dim3(8, 6), 256, 0, stream>>>(cat, Wout, bout, x_in, ao, 3328, 384, 0);
  k_ln<<<512, 64, 0, stream>>>(ao, attn_g, attn_b, xln);
  // FF chain
  k_gemm<<<dim3(8, 6), 256, 0, stream>>>(xln, W1, b1, nullptr, ffa, 384, 384, 1);
  k_gemm<<<dim3(8, 6), 256, 0, stream>>>(ffa, W2, b2, nullptr, ffb, 384, 384, 1);
  k_gemm<<<dim3(8, 6), 256, 0, stream>>>(ffb, W3, b3, xln, ao, 384, 384, 0);
  k_ln<<<512, 64, 0, stream>>>(ao, ff_g, ff_b, x2);
  k_final<<<8, 64, 0, stream>>>(x2, Wproj, bproj, quat, trans, Rm, (float*)d_out);
}

// Round 2
// 1023.533 us; speedup vs baseline: 1.5313x; 1.5313x over previous
//
#include <hip/hip_runtime.h>
#include <math.h>

#define SCALAR_SCALE 0.14433756729740643f  /* 1/sqrt(48) */
#define POINT_SCALE  0.13608276348795434f  /* 1/sqrt(54) */
#define PAIR_SCALE   0.5773502691896258f   /* 1/sqrt(3)  */

// ---------------------------------------------------------------------------
// Kernel A: pair_bias[h][i][j] = bpb[h] + sum_d pair[i][j][d] * Wpb[d][h]
// One wave handles 8 consecutive (i,j) pairs. lane = h*8+g; lane sums 48 d's.
// ---------------------------------------------------------------------------
__global__ __launch_bounds__(256) void k_pair_bias(
    const float* __restrict__ pair, const float* __restrict__ Wpb,
    const float* __restrict__ bpb, float* __restrict__ pb) {
  __shared__ float sW[384 * 8];
  for (int t = threadIdx.x; t < 384 * 8; t += 256) sW[t] = Wpb[t];
  __syncthreads();
  int wave = threadIdx.x >> 6;
  int lane = threadIdx.x & 63;
  int h = lane >> 3, g = lane & 7;
  float w[48];
#pragma unroll
  for (int k = 0; k < 48; ++k) w[k] = sW[(g * 48 + k) * 8 + h];
  int gw = blockIdx.x * 4 + wave;   // global wave id, 32768 total
  int p0 = gw * 8;                  // first pair index
  int i = p0 >> 9;
  int j0 = p0 & 511;
  const float* base = pair + ((size_t)(i * 512 + j0)) * 384 + g * 48;
  float acc[8];
#pragma unroll
  for (int jo = 0; jo < 8; ++jo) {
    const float4* p4 = (const float4*)(base + jo * 384);
    float a = 0.f;
#pragma unroll
    for (int k = 0; k < 12; ++k) {
      float4 v = p4[k];
      a = fmaf(v.x, w[k * 4 + 0], a);
      a = fmaf(v.y, w[k * 4 + 1], a);
      a = fmaf(v.z, w[k * 4 + 2], a);
      a = fmaf(v.w, w[k * 4 + 3], a);
    }
    acc[jo] = a;
  }
#pragma unroll
  for (int m = 1; m <= 4; m <<= 1) {
#pragma unroll
    for (int jo = 0; jo < 8; ++jo) acc[jo] += __shfl_xor(acc[jo], m, 64);
  }
  float outv = acc[0];
#pragma unroll
  for (int jo = 1; jo < 8; ++jo) if (g == jo) outv = acc[jo];
  pb[((h * 512 + i) << 9) + j0 + g] = outv + bpb[h];
}

// ---------------------------------------------------------------------------
// Wcat[d][c], c in [0,672): concat of Wsq|Wsk|Wsv|Wpq|Wpk|Wpv columns
// ---------------------------------------------------------------------------
__global__ __launch_bounds__(256) void k_wcat(
    const float* __restrict__ Wsq, const float* __restrict__ Wsk,
    const float* __restrict__ Wsv, const float* __restrict__ Wpq,
    const float* __restrict__ Wpk, const float* __restrict__ Wpv,
    float* __restrict__ wcat) {
  int idx = blockIdx.x * 256 + threadIdx.x;  // < 384*672
  int d = idx / 672, c = idx - d * 672;
  const float* W; int stride, coff;
  if (c < 128)      { W = Wsq; stride = 128; coff = c; }
  else if (c < 256) { W = Wsk; stride = 128; coff = c - 128; }
  else if (c < 384) { W = Wsv; stride = 128; coff = c - 256; }
  else if (c < 480) { W = Wpq; stride = 96;  coff = c - 384; }
  else if (c < 576) { W = Wpk; stride = 96;  coff = c - 480; }
  else              { W = Wpv; stride = 96;  coff = c - 576; }
  wcat[idx] = W[d * stride + coff];
}

// ---------------------------------------------------------------------------
// Split-K GEMM: part[z][row][col] = A[row][k0:k1] @ W[k0:k1][col]
// 32x32 tile, 2x2 per thread, 256 threads. M fixed at 512 (part stride).
// ---------------------------------------------------------------------------
__global__ __launch_bounds__(256) void k_gemm2(
    const float* __restrict__ A, const float* __restrict__ W,
    float* __restrict__ part, int K, int Ncols, int kchunk) {
  __shared__ float As[32][34];   // transposed: As[k][r]
  __shared__ float Ws[32][34];   // Ws[k][c]
  int rb = blockIdx.x << 5, cb = blockIdx.y << 5;
  int k0 = blockIdx.z * kchunk;
  int k1 = k0 + kchunk; if (k1 > K) k1 = K;
  int tr = ((threadIdx.x >> 4) << 1), tc = ((threadIdx.x & 15) << 1);
  float a00 = 0.f, a01 = 0.f, a10 = 0.f, a11 = 0.f;
  for (int kb = k0; kb < k1; kb += 32) {
    __syncthreads();
    for (int t = threadIdx.x; t < 1024; t += 256) {
      int r = t >> 5, k = t & 31;
      As[k][r] = A[(size_t)(rb + r) * K + kb + k];
      Ws[r][k] = W[(size_t)(kb + r) * Ncols + cb + k];
    }
    __syncthreads();
#pragma unroll
    for (int k = 0; k < 32; ++k) {
      float2 av = *(const float2*)&As[k][tr];
      float2 wv = *(const float2*)&Ws[k][tc];
      a00 = fmaf(av.x, wv.x, a00);
      a01 = fmaf(av.x, wv.y, a01);
      a10 = fmaf(av.y, wv.x, a10);
      a11 = fmaf(av.y, wv.y, a11);
    }
  }
  int row = rb + tr, col = cb + tc;
  float* p = part + ((size_t)blockIdx.z * 512 + row) * Ncols + col;
  p[0] = a00; p[1] = a01; p[Ncols] = a10; p[Ncols + 1] = a11;
}

// ---------------------------------------------------------------------------
// Reduce split-K partials: out = [relu]( sum_z part + bias + resid )
// ---------------------------------------------------------------------------
__global__ __launch_bounds__(256) void k_reduce(
    const float* __restrict__ part, const float* __restrict__ bias,
    const float* __restrict__ resid, float* __restrict__ out,
    int KS, int Ncols, int relu) {
  int idx = blockIdx.x * 256 + threadIdx.x;  // < 512*Ncols
  int col = idx % Ncols;
  float v = bias ? bias[col] : 0.f;
  for (int z = 0; z < KS; ++z) v += part[(size_t)z * 512 * Ncols + idx];
  if (resid) v += resid[idx];
  if (relu) v = fmaxf(v, 0.f);
  out[idx] = v;
}

// ---------------------------------------------------------------------------
// Kernel B2: per-n — R from quaternion, reshape qs/ks/vs, rotate qp/kp/vp,
// q2/k2 precompute. Layouts: s: [h][n][16], p: [h][n][12].
// ---------------------------------------------------------------------------
__global__ __launch_bounds__(64) void k_prep(
    const float* __restrict__ raw, const float* __restrict__ quat,
    const float* __restrict__ trans,
    float* __restrict__ qs, float* __restrict__ ks, float* __restrict__ vs,
    float* __restrict__ qp, float* __restrict__ kp, float* __restrict__ vp,
    float* __restrict__ q2, float* __restrict__ k2, float* __restrict__ Rm) {
  int n = blockIdx.x * 64 + threadIdx.x;
  float qw = quat[n * 4 + 0], qx = quat[n * 4 + 1];
  float qy = quat[n * 4 + 2], qz = quat[n * 4 + 3];
  float ss = 2.f / (qw * qw + qx * qx + qy * qy + qz * qz);
  float R00 = 1.f - ss * (qy * qy + qz * qz);
  float R01 = ss * (qx * qy - qz * qw);
  float R02 = ss * (qx * qz + qy * qw);
  float R10 = ss * (qx * qy + qz * qw);
  float R11 = 1.f - ss * (qx * qx + qz * qz);
  float R12 = ss * (qy * qz - qx * qw);
  float R20 = ss * (qx * qz - qy * qw);
  float R21 = ss * (qy * qz + qx * qw);
  float R22 = 1.f - ss * (qx * qx + qy * qy);
  float* Rr = Rm + n * 9;
  Rr[0] = R00; Rr[1] = R01; Rr[2] = R02;
  Rr[3] = R10; Rr[4] = R11; Rr[5] = R12;
  Rr[6] = R20; Rr[7] = R21; Rr[8] = R22;
  float t0 = trans[n * 3 + 0], t1 = trans[n * 3 + 1], t2 = trans[n * 3 + 2];
  const float* rr = raw + n * 672;
  for (int h = 0; h < 8; ++h) {
    int bs = (h * 512 + n) * 16;
#pragma unroll
    for (int d = 0; d < 16; ++d) {
      qs[bs + d] = rr[h * 16 + d];
      ks[bs + d] = rr[128 + h * 16 + d];
      vs[bs + d] = rr[256 + h * 16 + d];
    }
    float q2s = 0.f, k2s = 0.f;
    int bp = (h * 512 + n) * 12;
#pragma unroll
    for (int d = 0; d < 4; ++d) {
      float c0, c1, c2, o0, o1, o2;
      c0 = rr[384 + h * 12 + d * 3 + 0];
      c1 = rr[384 + h * 12 + d * 3 + 1];
      c2 = rr[384 + h * 12 + d * 3 + 2];
      o0 = c0 * R00 + c1 * R10 + c2 * R20 + t0;
      o1 = c0 * R01 + c1 * R11 + c2 * R21 + t1;
      o2 = c0 * R02 + c1 * R12 + c2 * R22 + t2;
      qp[bp + d * 3 + 0] = o0; qp[bp + d * 3 + 1] = o1; qp[bp + d * 3 + 2] = o2;
      q2s += o0 * o0 + o1 * o1 + o2 * o2;
      c0 = rr[480 + h * 12 + d * 3 + 0];
      c1 = rr[480 + h * 12 + d * 3 + 1];
      c2 = rr[480 + h * 12 + d * 3 + 2];
      o0 = c0 * R00 + c1 * R10 + c2 * R20 + t0;
      o1 = c0 * R01 + c1 * R11 + c2 * R21 + t1;
      o2 = c0 * R02 + c1 * R12 + c2 * R22 + t2;
      kp[bp + d * 3 + 0] = o0; kp[bp + d * 3 + 1] = o1; kp[bp + d * 3 + 2] = o2;
      k2s += o0 * o0 + o1 * o1 + o2 * o2;
      c0 = rr[576 + h * 12 + d * 3 + 0];
      c1 = rr[576 + h * 12 + d * 3 + 1];
      c2 = rr[576 + h * 12 + d * 3 + 2];
      o0 = c0 * R00 + c1 * R10 + c2 * R20 + t0;
      o1 = c0 * R01 + c1 * R11 + c2 * R21 + t1;
      o2 = c0 * R02 + c1 * R12 + c2 * R22 + t2;
      vp[bp + d * 3 + 0] = o0; vp[bp + d * 3 + 1] = o1; vp[bp + d * 3 + 2] = o2;
    }
    q2[h * 512 + n] = q2s;
    k2[h * 512 + n] = k2s;
  }
}

// ---------------------------------------------------------------------------
// Kernel C: attention per (h,i). Logits -> softmax -> res_s/res_p.
// Writes normalized attn row (for res_pair pass) and cat[i] slices.
// ---------------------------------------------------------------------------
__global__ __launch_bounds__(256) void k_attn(
    const float* __restrict__ qs, const float* __restrict__ ks,
    const float* __restrict__ vs, const float* __restrict__ qp,
    const float* __restrict__ kp, const float* __restrict__ vp,
    const float* __restrict__ q2, const float* __restrict__ k2,
    const float* __restrict__ pb, const float* __restrict__ pw_raw,
    const float* __restrict__ Rm, const float* __restrict__ trans,
    float* __restrict__ attn, float* __restrict__ cat) {
  int i = blockIdx.x, h = blockIdx.y;
  int t = threadIdx.x;
  __shared__ float sq[16], sp[12];
  __shared__ float sattn[512];
  __shared__ float red[8][32];
  __shared__ float swr[4], sws[4];
  __shared__ float sres[28];
  if (t < 16) sq[t] = qs[((h << 9) + i) * 16 + t];
  else if (t < 28) sp[t - 16] = qp[((h << 9) + i) * 12 + (t - 16)];
  __syncthreads();
  float pwh = log1pf(expf(pw_raw[h]));  // softplus
  float q2i = q2[(h << 9) + i];
  float coef = 0.5f * POINT_SCALE * pwh;
  float lg[2];
#pragma unroll
  for (int p = 0; p < 2; ++p) {
    int j = t + (p << 8);
    const float4* k4 = (const float4*)(ks + ((h << 9) + j) * 16);
    float d16 = 0.f;
#pragma unroll
    for (int q4 = 0; q4 < 4; ++q4) {
      float4 kv = k4[q4];
      d16 = fmaf(kv.x, sq[q4 * 4 + 0], d16);
      d16 = fmaf(kv.y, sq[q4 * 4 + 1], d16);
      d16 = fmaf(kv.z, sq[q4 * 4 + 2], d16);
      d16 = fmaf(kv.w, sq[q4 * 4 + 3], d16);
    }
    const float4* p4 = (const float4*)(kp + ((h << 9) + j) * 12);
    float d12 = 0.f;
#pragma unroll
    for (int q4 = 0; q4 < 3; ++q4) {
      float4 kv = p4[q4];
      d12 = fmaf(kv.x, sp[q4 * 4 + 0], d12);
      d12 = fmaf(kv.y, sp[q4 * 4 + 1], d12);
      d12 = fmaf(kv.z, sp[q4 * 4 + 2], d12);
      d12 = fmaf(kv.w, sp[q4 * 4 + 3], d12);
    }
    float dist = q2i + k2[(h << 9) + j] - 2.f * d12;
    lg[p] = SCALAR_SCALE * d16 - coef * dist +
            PAIR_SCALE * pb[(((h << 9) + i) << 9) + j];
  }
  float mx = fmaxf(lg[0], lg[1]);
#pragma unroll
  for (int m = 1; m < 64; m <<= 1) mx = fmaxf(mx, __shfl_xor(mx, m, 64));
  if ((t & 63) == 0) swr[t >> 6] = mx;
  __syncthreads();
  mx = fmaxf(fmaxf(swr[0], swr[1]), fmaxf(swr[2], swr[3]));
  float e0 = expf(lg[0] - mx), e1 = expf(lg[1] - mx);
  float sm = e0 + e1;
#pragma unroll
  for (int m = 1; m < 64; m <<= 1) sm += __shfl_xor(sm, m, 64);
  if ((t & 63) == 0) sws[t >> 6] = sm;
  __syncthreads();
  sm = sws[0] + sws[1] + sws[2] + sws[3];
  float inv = 1.f / sm;
  e0 *= inv; e1 *= inv;
  sattn[t] = e0; sattn[t + 256] = e1;
  {
    float* arow = attn + ((size_t)(((h << 9) + i)) << 9);
    arow[t] = e0; arow[t + 256] = e1;
  }
  __syncthreads();
  int o = t & 31, g = t >> 5;
  float partial = 0.f;
  if (o < 28) {
    const float* src; int stride;
    if (o < 16) { src = vs + (h << 9) * 16 + o; stride = 16; }
    else        { src = vp + (h << 9) * 12 + (o - 16); stride = 12; }
    int j0 = g << 6;
    for (int j = j0; j < j0 + 64; ++j)
      partial = fmaf(sattn[j], src[j * stride], partial);
  }
  red[g][o] = partial;
  __syncthreads();
  if (t < 28) {
    float r2 = 0.f;
#pragma unroll
    for (int gg = 0; gg < 8; ++gg) r2 += red[gg][t];
    sres[t] = r2;
  }
  __syncthreads();
  float* crow = cat + i * 3328;
  if (t < 16) {
    crow[h * 16 + t] = sres[t];
  } else if (t < 20) {
    int d = t - 16;
    float t0 = trans[i * 3], t1 = trans[i * 3 + 1], t2 = trans[i * 3 + 2];
    float c0 = sres[16 + d * 3 + 0] - t0;
    float c1 = sres[16 + d * 3 + 1] - t1;
    float c2 = sres[16 + d * 3 + 2] - t2;
    const float* R = Rm + i * 9;
    float l0 = c0 * R[0] + c1 * R[1] + c2 * R[2];
    float l1 = c0 * R[3] + c1 * R[4] + c2 * R[5];
    float l2 = c0 * R[6] + c1 * R[7] + c2 * R[8];
    crow[128 + h * 12 + d * 3 + 0] = l0;
    crow[128 + h * 12 + d * 3 + 1] = l1;
    crow[128 + h * 12 + d * 3 + 2] = l2;
    crow[224 + h * 4 + d] = sqrtf(l0 * l0 + l1 * l1 + l2 * l2 + 1e-8f);
  }
}

// ---------------------------------------------------------------------------
// Kernel D: res_pair[h][i][d] = sum_j attn[h][i][j] * pair[i][j][d]
// Block per i, thread per d (384 threads), attn rows in LDS.
// ---------------------------------------------------------------------------
__global__ __launch_bounds__(384) void k_respair(
    const float* __restrict__ attn, const float* __restrict__ pair,
    float* __restrict__ cat) {
  __shared__ float sa[8][512];
  int i = blockIdx.x;
  for (int t = threadIdx.x; t < 4096; t += 384) {
    int h = t >> 9, j = t & 511;
    sa[h][j] = attn[((size_t)(h * 512 + i) << 9) + j];
  }
  __syncthreads();
  int d = threadIdx.x;
  float acc[8] = {0.f, 0.f, 0.f, 0.f, 0.f, 0.f, 0.f, 0.f};
  const float* p = pair + (size_t)i * 512 * 384 + d;
  for (int j = 0; j < 512; j += 4) {
    float v0 = p[(size_t)(j + 0) * 384];
    float v1 = p[(size_t)(j + 1) * 384];
    float v2 = p[(size_t)(j + 2) * 384];
    float v3 = p[(size_t)(j + 3) * 384];
#pragma unroll
    for (int h = 0; h < 8; ++h) {
      float4 a4 = *(const float4*)&sa[h][j];
      acc[h] = fmaf(a4.x, v0, acc[h]);
      acc[h] = fmaf(a4.y, v1, acc[h]);
      acc[h] = fmaf(a4.z, v2, acc[h]);
      acc[h] = fmaf(a4.w, v3, acc[h]);
    }
  }
#pragma unroll
  for (int h = 0; h < 8; ++h) cat[i * 3328 + 256 + h * 384 + d] = acc[h];
}

// ---------------------------------------------------------------------------
// LayerNorm over D=384, one wave per row.
// ---------------------------------------------------------------------------
__global__ __launch_bounds__(64) void k_ln(
    const float* __restrict__ in, const float* __restrict__ gw,
    const float* __restrict__ bw, float* __restrict__ out) {
  int n = blockIdx.x, lane = threadIdx.x;
  float v[6];
  float s1 = 0.f, s2 = 0.f;
#pragma unroll
  for (int k = 0; k < 3; ++k) {
    float2 xv = *(const float2*)(in + n * 384 + (k << 7) + (lane << 1));
    v[k * 2] = xv.x; v[k * 2 + 1] = xv.y;
    s1 += xv.x + xv.y;
    s2 = fmaf(xv.x, xv.x, fmaf(xv.y, xv.y, s2));
  }
#pragma unroll
  for (int m = 1; m < 64; m <<= 1) {
    s1 += __shfl_xor(s1, m, 64);
    s2 += __shfl_xor(s2, m, 64);
  }
  float mean = s1 * (1.f / 384.f);
  float var = s2 * (1.f / 384.f) - mean * mean;
  float inv = 1.f / sqrtf(var + 1e-5f);
#pragma unroll
  for (int k = 0; k < 3; ++k) {
    int d = (k << 7) + (lane << 1);
    out[n * 384 + d]     = (v[k * 2]     - mean) * inv * gw[d]     + bw[d];
    out[n * 384 + d + 1] = (v[k * 2 + 1] - mean) * inv * gw[d + 1] + bw[d + 1];
  }
}

// ---------------------------------------------------------------------------
// Final: updates = x2 @ Wproj + bproj; quaternion multiply; translation update
// ---------------------------------------------------------------------------
__global__ __launch_bounds__(64) void k_final(
    const float* __restrict__ x2, const float* __restrict__ Wproj,
    const float* __restrict__ bproj, const float* __restrict__ quat,
    const float* __restrict__ trans, const float* __restrict__ Rm,
    float* __restrict__ out) {
  int n = blockIdx.x * 64 + threadIdx.x;
  float u0 = bproj[0], u1 = bproj[1], u2 = bproj[2];
  float u3 = bproj[3], u4 = bproj[4], u5 = bproj[5];
  const float* xr = x2 + n * 384;
  for (int d = 0; d < 384; ++d) {
    float xv = xr[d];
    const float* wr = Wproj + d * 6;
    u0 = fmaf(xv, wr[0], u0); u1 = fmaf(xv, wr[1], u1); u2 = fmaf(xv, wr[2], u2);
    u3 = fmaf(xv, wr[3], u3); u4 = fmaf(xv, wr[4], u4); u5 = fmaf(xv, wr[5], u5);
  }
  float aw = quat[n * 4 + 0], ax = quat[n * 4 + 1];
  float ay = quat[n * 4 + 2], az = quat[n * 4 + 3];
  float qw2 = aw - ax * u0 - ay * u1 - az * u2;
  float qx2 = aw * u0 + ax + ay * u2 - az * u1;
  float qy2 = aw * u1 - ax * u2 + ay + az * u0;
  float qz2 = aw * u2 + ax * u1 - ay * u0 + az;
  const float* R = Rm + n * 9;
  out[n * 3 + 0] = trans[n * 3 + 0] + u3 * R[0] + u4 * R[3] + u5 * R[6];
  out[n * 3 + 1] = trans[n * 3 + 1] + u3 * R[1] + u4 * R[4] + u5 * R[7];
  out[n * 3 + 2] = trans[n * 3 + 2] + u3 * R[2] + u4 * R[5] + u5 * R[8];
  out[1536 + n * 4 + 0] = qw2;
  out[1536 + n * 4 + 1] = qx2;
  out[1536 + n * 4 + 2] = qy2;
  out[1536 + n * 4 + 3] = qz2;
}

// ---------------------------------------------------------------------------
extern "C" void kernel_launch(void* const* d_in, const int* in_sizes, int n_in,
                              void* d_out, int out_size, void* d_ws,
                              size_t ws_size, hipStream_t stream) {
  const float* x_in   = (const float*)d_in[0];
  const float* pair   = (const float*)d_in[1];
  const float* trans  = (const float*)d_in[2];
  const float* quat   = (const float*)d_in[3];
  const float* Wsq    = (const float*)d_in[4];
  const float* Wsk    = (const float*)d_in[5];
  const float* Wsv    = (const float*)d_in[6];
  const float* Wpq    = (const float*)d_in[7];
  const float* Wpk    = (const float*)d_in[8];
  const float* Wpv    = (const float*)d_in[9];
  const float* pw     = (const float*)d_in[10];
  const float* Wpb    = (const float*)d_in[11];
  const float* bpb    = (const float*)d_in[12];
  const float* Wout   = (const float*)d_in[13];
  const float* bout   = (const float*)d_in[14];
  const float* attn_g = (const float*)d_in[15];
  const float* attn_b = (const float*)d_in[16];
  const float* W1     = (const float*)d_in[17];
  const float* b1     = (const float*)d_in[18];
  const float* W2     = (const float*)d_in[19];
  const float* b2     = (const float*)d_in[20];
  const float* W3     = (const float*)d_in[21];
  const float* b3     = (const float*)d_in[22];
  const float* ff_g   = (const float*)d_in[23];
  const float* ff_b   = (const float*)d_in[24];
  const float* Wproj  = (const float*)d_in[25];
  const float* bproj  = (const float*)d_in[26];

  float* ws   = (float*)d_ws;
  float* pb   = ws + 0;         // 2,097,152  (also aliased as split-K partials)
  float* attn = ws + 2097152;   // 2,097,152
  float* raw  = ws + 4194304;   //   344,064
  float* qs   = ws + 4538368;   //    65,536
  float* ks_  = ws + 4603904;   //    65,536
  float* vs   = ws + 4669440;   //    65,536
  float* qp   = ws + 4734976;   //    49,152
  float* kp   = ws + 4784128;   //    49,152
  float* vp   = ws + 4833280;   //    49,152
  float* q2   = ws + 4882432;   //     4,096
  float* k2   = ws + 4886528;   //     4,096
  float* Rm   = ws + 4890624;   //     4,608
  float* cat  = ws + 4895232;   // 1,703,936
  float* ao   = ws + 6599168;   //   196,608
  float* xln  = ws + 6795776;   //   196,608
  float* ffa  = ws + 6992384;   //   196,608
  float* ffb  = ws + 7188992;   //   196,608
  float* x2   = ws + 7385600;   //   196,608
  float* wcat = ws + 7582208;   //   258,048  (total 7,840,256 f32 = 31.4 MB)
  float* part = pb;             // alias: pb dead after k_attn; part live only
                                // during proj-GEMM (before pair_bias) and the
                                // post-attention GEMM chain.

  // QKV projections: raw = x @ Wcat  (split-K, partials in `part`)
  k_wcat<<<1008, 256, 0, stream>>>(Wsq, Wsk, Wsv, Wpq, Wpk, Wpv, wcat);
  k_gemm2<<<dim3(16, 21, 2), 256, 0, stream>>>(x_in, wcat, part, 384, 672, 192);
  k_reduce<<<1344, 256, 0, stream>>>(part, nullptr, nullptr, raw, 2, 672, 0);
  k_prep<<<8, 64, 0, stream>>>(raw, quat, trans, qs, ks_, vs, qp, kp, vp, q2, k2, Rm);
  // pair bias (overwrites `part` alias region — partials already consumed)
  k_pair_bias<<<8192, 256, 0, stream>>>(pair, Wpb, bpb, pb);
  k_attn<<<dim3(512, 8), 256, 0, stream>>>(qs, ks_, vs, qp, kp, vp, q2, k2, pb,
                                           pw, Rm, trans, attn, cat);
  k_respair<<<512, 384, 0, stream>>>(attn, pair, cat);
  // attn_out = cat @ Wout + bout + x ; LN
  k_gemm2<<<dim3(16, 12, 4), 256, 0, stream>>>(cat, Wout, part, 3328, 384, 832);
  k_reduce<<<768, 256, 0, stream>>>(part, bout, x_in, ao, 4, 384, 0);
  k_ln<<<512, 64, 0, stream>>>(ao, attn_g, attn_b, xln);
  // FF chain
  k_gemm2<<<dim3(16, 12, 2), 256, 0, stream>>>(xln, W1, part, 384, 384, 192);
  k_reduce<<<768, 256, 0, stream>>>(part, b1, nullptr, ffa, 2, 384, 1);
  k_gemm2<<<dim3(16, 12, 2), 256, 0, stream>>>(ffa, W2, part, 384, 384, 192);
  k_reduce<<<768, 256, 0, stream>>>(part, b2, nullptr, ffb, 2, 384, 1);
  k_gemm2<<<dim3(16, 12, 2), 256, 0, stream>>>(ffb, W3, part, 384, 384, 192);
  k_reduce<<<768, 256, 0, stream>>>(part, b3, xln, ao, 2, 384, 0);
  k_ln<<<512, 64, 0, stream>>>(ao, ff_g, ff_b, x2);
  k_final<<<8, 64, 0, stream>>>(x2, Wproj, bproj, quat, trans, Rm, (float*)d_out);
}